// Round 1
// baseline (1097.606 us; speedup 1.0000x reference)
//
#include <hip/hip_runtime.h>

#define NEGV (-10000.0f)

constexpr int Bb  = 512;
constexpr int Ss  = 1024;
constexpr int Tt  = 64;
constexpr int Kc  = 32;          // backtrace chunk length
constexpr int NCH = Ss / Kc;     // 32 chunks

// ---------------- forward Viterbi: one wave (64 lanes) per batch ----------------
__global__ __launch_bounds__(64) void viterbi_fwd(
    const float* __restrict__ feats,      // [B,S,T]
    const float* __restrict__ trans,      // [T,T] (next, prev)
    float* __restrict__ path_score,       // [B] -> d_out[0..511]
    unsigned char* __restrict__ bp,       // [S,B,T] backpointers
    unsigned char* __restrict__ ccomp,    // [NCH,B,T] composed chunk jumps
    int* __restrict__ best_tag)           // [B]
{
    const int b    = blockIdx.x;
    const int lane = threadIdx.x;

    __shared__ float fvs[2][Tt];

    // Each lane holds transition row for next-tag = lane (constant all steps).
    float trow[Tt];
#pragma unroll
    for (int p4 = 0; p4 < 16; ++p4) {
        float4 t4 = reinterpret_cast<const float4*>(trans)[lane * 16 + p4];
        trow[4*p4+0] = t4.x; trow[4*p4+1] = t4.y;
        trow[4*p4+2] = t4.z; trow[4*p4+3] = t4.w;
    }

    float fv  = (lane == 62) ? 0.0f : NEGV;   // START_IX = 62
    int  comp = lane;                          // composed jump within chunk
    const float* fb = feats + (size_t)b * Ss * Tt;
    float feat = fb[lane];                     // feat for step 0
    unsigned char* bpp = bp + (size_t)b * Tt + lane;

    for (int s = 0; s < Ss; ++s) {
        fvs[s & 1][lane] = fv;
        __syncthreads();
        float featn = (s + 1 < Ss) ? fb[(size_t)(s + 1) * Tt + lane] : 0.0f;

        const float4* f4 = reinterpret_cast<const float4*>(fvs[s & 1]);
        // 4 independent chains of 16 contiguous candidates; strict-> keeps first max.
        float m[4]; int ix[4];
#pragma unroll
        for (int c = 0; c < 4; ++c) { m[c] = -3.4e38f; ix[c] = 0; }
#pragma unroll
        for (int p4 = 0; p4 < 16; ++p4) {
            const int c = p4 >> 2;
            float4 v = f4[p4];       // uniform-address broadcast read
            float c0 = v.x + trow[4*p4+0];
            float c1 = v.y + trow[4*p4+1];
            float c2 = v.z + trow[4*p4+2];
            float c3 = v.w + trow[4*p4+3];
            bool g;
            g = c0 > m[c]; m[c] = g ? c0 : m[c]; ix[c] = g ? 4*p4+0 : ix[c];
            g = c1 > m[c]; m[c] = g ? c1 : m[c]; ix[c] = g ? 4*p4+1 : ix[c];
            g = c2 > m[c]; m[c] = g ? c2 : m[c]; ix[c] = g ? 4*p4+2 : ix[c];
            g = c3 > m[c]; m[c] = g ? c3 : m[c]; ix[c] = g ? 4*p4+3 : ix[c];
        }
        float mb = m[0]; int ib = ix[0];
#pragma unroll
        for (int c = 1; c < 4; ++c) {           // ascending, strict > => first max
            bool g = m[c] > mb; mb = g ? m[c] : mb; ib = g ? ix[c] : ib;
        }

        bpp[(size_t)s * (Bb * Tt)] = (unsigned char)ib;   // bp[s][b][lane]

        // composed jump update: comp_new[t] = comp[bp_s[t]]
        comp = __shfl(comp, ib);
        if (((s + 1) & (Kc - 1)) == 0) {
            int c = (s + 1) / Kc - 1;
            ccomp[(size_t)c * (Bb * Tt) + b * Tt + lane] = (unsigned char)comp;
            comp = lane;
        }

        fv   = mb + feat;
        feat = featn;
    }

    // terminal: fv + transitions[END_IX=63][lane], wave argmax (tie -> lower index)
    float tm  = fv + trans[63 * Tt + lane];
    float m   = tm; int idx = lane;
#pragma unroll
    for (int off = 32; off >= 1; off >>= 1) {
        float mo = __shfl_xor(m, off);
        int   io = __shfl_xor(idx, off);
        bool take = (mo > m) || ((mo == m) && (io < idx));
        m = take ? mo : m; idx = take ? io : idx;
    }
    if (lane == 0) { path_score[b] = m; best_tag[b] = idx; }
}

// ---------------- backtrace: one block (64 threads) per batch ----------------
__global__ __launch_bounds__(64) void viterbi_back(
    const unsigned char* __restrict__ bp,
    const unsigned char* __restrict__ ccomp,
    const int* __restrict__ best_tag,
    float* __restrict__ best_path)        // [B,S] -> d_out + 512 (tags as float)
{
    const int b    = blockIdx.x;
    const int lane = threadIdx.x;
    __shared__ int btags[NCH];            // tag at END of chunk c

    if (lane == 0) {
        int tag = best_tag[b];            // tag at step S-1 (end of last chunk)
        for (int c = NCH - 1; c >= 0; --c) {
            btags[c] = tag;
            tag = ccomp[(size_t)c * (Bb * Tt) + b * Tt + tag]; // tag at c*K-1
        }
    }
    __syncthreads();

    if (lane < NCH) {
        const int c = lane;
        int tag = btags[c];
        for (int i = Kc - 1; i >= 0; --i) {
            int s = c * Kc + i;
            best_path[(size_t)b * Ss + s] = (float)tag;
            tag = bp[(size_t)s * (Bb * Tt) + b * Tt + tag];  // tag at s-1
        }
    }
}

extern "C" void kernel_launch(void* const* d_in, const int* in_sizes, int n_in,
                              void* d_out, int out_size, void* d_ws, size_t ws_size,
                              hipStream_t stream) {
    const float* feats = (const float*)d_in[0];   // [512,1024,64] f32
    const float* trans = (const float*)d_in[1];   // [64,64] f32

    float* path_score = (float*)d_out;            // [512]
    float* best_path  = (float*)d_out + Bb;       // [512,1024] tags as float

    // workspace layout
    unsigned char* bp    = (unsigned char*)d_ws;                       // 33,554,432 B
    unsigned char* ccomp = bp + (size_t)Ss * Bb * Tt;                  // 1,048,576 B
    int*           btag  = (int*)(ccomp + (size_t)NCH * Bb * Tt);      // 2048 B

    viterbi_fwd<<<Bb, 64, 0, stream>>>(feats, trans, path_score, bp, ccomp, btag);
    viterbi_back<<<Bb, 64, 0, stream>>>(bp, ccomp, btag, best_path);
}

// Round 5
// 591.101 us; speedup vs baseline: 1.8569x; 1.8569x over previous
//
#include <hip/hip_runtime.h>

#define NEGV (-10000.0f)

constexpr int Bb = 512;
constexpr int Ss = 1024;
constexpr int Tt = 64;

typedef __attribute__((address_space(1))) const unsigned int guint_t;
typedef __attribute__((address_space(3))) unsigned int luint_t;

// One block (256 threads = 4 waves) per batch. Wave w owns prev-tags [16w,16w+16).
// Lane l (0..63) owns next-tag l. Forward Viterbi + fused LDS backtrace.
__global__ __launch_bounds__(256, 2) void viterbi_fused(
    const float* __restrict__ feats,      // [B,S,T]
    const float* __restrict__ trans,      // [T,T] (next, prev)
    float* __restrict__ path_score,       // [B]
    float* __restrict__ best_path)        // [B,S] tags as float
{
    __shared__ float ftile[2][8][Tt];           // 4 KB  feats tiles (8 steps each)
    __shared__ uint2 partials[2][4][Tt];        // 4 KB  (max, argmax) per wave, dbuf
    __shared__ float fvb[4][16];                // 256 B per-wave fv broadcast
    __shared__ unsigned char bp_lds[Ss][Tt];    // 64 KB backpointers
    __shared__ unsigned char ccomp[32][Tt];     // 2 KB  composed chunk jumps
    __shared__ int btags[32];                   // 128 B

    const int b    = blockIdx.x;
    const int tid  = threadIdx.x;
    const int wid  = tid >> 6;
    const int lane = tid & 63;

    const float* fb = feats + (size_t)b * (Ss * Tt);

    // Per-lane transition slice: trans[lane][wid*16 .. wid*16+16)  (16 VGPRs)
    const float* tr = trans + lane * Tt + (wid << 4);
    float4 t0 = *(const float4*)(tr + 0);
    float4 t1 = *(const float4*)(tr + 4);
    float4 t2 = *(const float4*)(tr + 8);
    float4 t3 = *(const float4*)(tr + 12);
    float tend = trans[63 * Tt + lane];   // terminal row (END_IX = 63)

    // Prologue: stage tile 0 (steps 0..7) into LDS via async DMA (wave 0).
    if (wid == 0) {
#pragma unroll
        for (int i = 0; i < 2; ++i)
            __builtin_amdgcn_global_load_lds(
                (guint_t*)(fb + i * 256 + lane * 4),
                (luint_t*)((unsigned int*)&ftile[0][0][0] + i * 256),
                16, 0, 0);
        asm volatile("s_waitcnt vmcnt(0)" ::: "memory");
    }
    __syncthreads();

    float fv  = (lane == 62) ? 0.0f : NEGV;   // START_IX = 62
    int  comp = lane;                          // wave 0 maintains composed jumps

    for (int t = 0; t < 128; ++t) {
        // Issue async loads for the next 8-step tile (wave 0 only).
        if (wid == 0 && t + 1 < 128) {
            const float* src = fb + (size_t)(t + 1) * 512;
            unsigned int* dst = (unsigned int*)&ftile[(t + 1) & 1][0][0];
#pragma unroll
            for (int i = 0; i < 2; ++i)
                __builtin_amdgcn_global_load_lds(
                    (guint_t*)(src + i * 256 + lane * 4),
                    (luint_t*)(dst + i * 256),
                    16, 0, 0);
        }
#pragma unroll
        for (int i = 0; i < 8; ++i) {
            const int s = t * 8 + i;
            float featv = ftile[t & 1][i][lane];

            // Broadcast this wave's 16 prev fv values (they live in lanes [16w,16w+16)).
            if ((lane >> 4) == wid) fvb[wid][lane & 15] = fv;
            float4 q0 = *(float4*)&fvb[wid][0];
            float4 q1 = *(float4*)&fvb[wid][4];
            float4 q2 = *(float4*)&fvb[wid][8];
            float4 q3 = *(float4*)&fvb[wid][12];

            // 16 candidates, 4 independent chains, strict-> keeps first max.
            float mq0, mq1, mq2, mq3; int xq0, xq1, xq2, xq3;
#define QUAD(K, QV, TV, MQ, XQ) { \
            float ca = QV.x + TV.x, cb = QV.y + TV.y, cc = QV.z + TV.z, cd = QV.w + TV.w; \
            float mm = ca; int xx = 4*K + 0; \
            if (cb > mm) { mm = cb; xx = 4*K + 1; } \
            if (cc > mm) { mm = cc; xx = 4*K + 2; } \
            if (cd > mm) { mm = cd; xx = 4*K + 3; } \
            MQ = mm; XQ = xx; }
            QUAD(0, q0, t0, mq0, xq0)
            QUAD(1, q1, t1, mq1, xq1)
            QUAD(2, q2, t2, mq2, xq2)
            QUAD(3, q3, t3, mq3, xq3)
#undef QUAD
            float mp = mq0; int xp = xq0;
            if (mq1 > mp) { mp = mq1; xp = xq1; }
            if (mq2 > mp) { mp = mq2; xp = xq2; }
            if (mq3 > mp) { mp = mq3; xp = xq3; }
            int gix = (wid << 4) + xp;         // global prev index

            partials[i & 1][wid][lane] = make_uint2(__float_as_uint(mp), (unsigned)gix);

            // Tile-boundary discipline: DMA drained before the barrier that
            // releases other waves into the next tile; reads consumed pre-barrier.
            if (i == 7) {
                asm volatile("" : "+v"(featv));
                if (wid == 0) asm volatile("s_waitcnt vmcnt(0)" ::: "memory");
            }
            __syncthreads();

            uint2 r0 = partials[i & 1][0][lane];
            uint2 r1 = partials[i & 1][1][lane];
            uint2 r2 = partials[i & 1][2][lane];
            uint2 r3 = partials[i & 1][3][lane];
            float mb = __uint_as_float(r0.x); int ib = (int)r0.y;
            float mw;
            mw = __uint_as_float(r1.x); if (mw > mb) { mb = mw; ib = (int)r1.y; }
            mw = __uint_as_float(r2.x); if (mw > mb) { mb = mw; ib = (int)r2.y; }
            mw = __uint_as_float(r3.x); if (mw > mb) { mb = mw; ib = (int)r3.y; }

            if (wid == 0) {
                bp_lds[s][lane] = (unsigned char)ib;
                comp = __shfl(comp, ib);
                if ((s & 31) == 31) { ccomp[s >> 5][lane] = (unsigned char)comp; comp = lane; }
            }
            fv = mb + featv;
        }
    }

    // Terminal: fv + trans[END][lane]; wave-0 argmax (tie -> lower index).
    if (wid == 0) {
        float mr = fv + tend; int ir = lane;
#pragma unroll
        for (int off = 32; off >= 1; off >>= 1) {
            float mo = __shfl_xor(mr, off);
            int   io = __shfl_xor(ir, off);
            bool take = (mo > mr) || ((mo == mr) && (io < ir));
            mr = take ? mo : mr; ir = take ? io : ir;
        }
        if (lane == 0) {
            path_score[b] = mr;
            int tag = ir;
            for (int c = 31; c >= 0; --c) {    // serial chunk-tag chase in LDS
                btags[c] = tag;
                tag = ccomp[c][tag];
            }
        }
    }
    __syncthreads();

    // Parallel in-chunk backtrace: lane c handles steps [32c, 32c+32).
    if (wid == 0 && lane < 32) {
        int tag = btags[lane];
        float* op = best_path + (size_t)b * Ss + lane * 32;
        for (int i = 31; i >= 0; --i) {
            op[i] = (float)tag;
            tag = bp_lds[lane * 32 + i][tag];
        }
    }
}

extern "C" void kernel_launch(void* const* d_in, const int* in_sizes, int n_in,
                              void* d_out, int out_size, void* d_ws, size_t ws_size,
                              hipStream_t stream) {
    const float* feats = (const float*)d_in[0];   // [512,1024,64] f32
    const float* trans = (const float*)d_in[1];   // [64,64] f32

    float* path_score = (float*)d_out;            // [512]
    float* best_path  = (float*)d_out + Bb;       // [512,1024] tags as float

    viterbi_fused<<<Bb, 256, 0, stream>>>(feats, trans, path_score, best_path);
}